// Round 5
// baseline (226.706 us; speedup 1.0000x reference)
//
#include <hip/hip_runtime.h>
#include <math.h>

// (B,C,H,W) = (16,64,256,256)
// out[b,d,hw] = relu( rrelu( sum_c mix[d,c]*softmax_c(x)[b,c,hw] + bias[d] ) + 0.1*x[b,d,hw] )
#define HWSZ 65536

typedef __bf16 bf16x8 __attribute__((ext_vector_type(8)));
typedef __bf16 bf16x4 __attribute__((ext_vector_type(4)));
typedef float f32x4 __attribute__((ext_vector_type(4)));

__global__ __launch_bounds__(256) void cvt_mix_kernel(const float* __restrict__ mix,
                                                      __bf16* __restrict__ mixb) {
    int i = blockIdx.x * 256 + threadIdx.x;   // 4096 elements
    mixb[i] = (__bf16)mix[i];
}

// softmax over e[64]; writes swizzled bf16 s-row `lane`; returns M = m + ln(sum).
// e[] is DEAD on return (safe to overwrite with prefetch loads).
__device__ __forceinline__ float softmax_to_lds(float (&e)[64], __bf16* my, int lane) {
    const float LOG2E = 1.44269504088896340736f;
    const float LN2   = 0.69314718055994530942f;
    float m0 = e[0], m1 = e[1], m2 = e[2], m3 = e[3];
#pragma unroll
    for (int c = 4; c < 64; c += 4) {
        m0 = fmaxf(m0, e[c]);     m1 = fmaxf(m1, e[c + 1]);
        m2 = fmaxf(m2, e[c + 2]); m3 = fmaxf(m3, e[c + 3]);
    }
    const float m = fmaxf(fmaxf(m0, m1), fmaxf(m2, m3));
    float s0 = 0.f, s1 = 0.f, s2 = 0.f, s3 = 0.f;
#pragma unroll
    for (int c = 0; c < 64; c += 4) {
        e[c]     = __builtin_exp2f((e[c]     - m) * LOG2E); s0 += e[c];
        e[c + 1] = __builtin_exp2f((e[c + 1] - m) * LOG2E); s1 += e[c + 1];
        e[c + 2] = __builtin_exp2f((e[c + 2] - m) * LOG2E); s2 += e[c + 2];
        e[c + 3] = __builtin_exp2f((e[c + 3] - m) * LOG2E); s3 += e[c + 3];
    }
    const float sum = (s0 + s1) + (s2 + s3);
    const float inv = 1.f / sum;
#pragma unroll
    for (int j = 0; j < 8; ++j) {
        bf16x8 v;
#pragma unroll
        for (int i = 0; i < 8; ++i) v[i] = (__bf16)(e[j * 8 + i] * inv);
        const int gr = j ^ (lane & 7);                    // 16B-granule XOR swizzle
        *reinterpret_cast<bf16x8*>(my + lane * 64 + gr * 8) = v;
    }
    return fmaf(LN2, __builtin_log2f(sum), m);
}

// MFMA matvec + bias/RReLU/0.1x/ReLU epilogue for one tile (ob = out + tile base)
__device__ __forceinline__ void mfma_epilogue(const __bf16* my, const __bf16* mixb,
                                              const float* bias, float* ob,
                                              const float (&Mp)[4], int l15, int lhi) {
    const float LN2 = 0.69314718055994530942f;
#pragma unroll
    for (int mtp = 0; mtp < 2; ++mtp) {
        f32x4 acc[2][4] = {};
#pragma unroll
        for (int kt = 0; kt < 2; ++kt) {
            const __bf16* ab = mixb + (mtp * 32 + l15) * 64 + kt * 32 + lhi * 8;
            const bf16x8 A0 = *reinterpret_cast<const bf16x8*>(ab);
            const bf16x8 A1 = *reinterpret_cast<const bf16x8*>(ab + 16 * 64);
#pragma unroll
            for (int nt = 0; nt < 4; ++nt) {              // one B live at a time
                const int row = nt * 16 + l15;            // pixel
                const int g = (kt * 4 + lhi) ^ (row & 7);
                const bf16x8 B = *reinterpret_cast<const bf16x8*>(my + row * 64 + g * 8);
                acc[0][nt] = __builtin_amdgcn_mfma_f32_16x16x32_bf16(A0, B, acc[0][nt], 0, 0, 0);
                acc[1][nt] = __builtin_amdgcn_mfma_f32_16x16x32_bf16(A1, B, acc[1][nt], 0, 0, 0);
            }
        }
#pragma unroll
        for (int mt = 0; mt < 2; ++mt) {
            const int d0 = mtp * 32 + mt * 16 + lhi * 4;
            const float bb[4] = {bias[d0], bias[d0 + 1], bias[d0 + 2], bias[d0 + 3]};
#pragma unroll
            for (int nt = 0; nt < 4; ++nt) {
                const int p = nt * 16 + l15;
                const int g = ((d0 >> 3) ^ (p & 7));      // 8B-aligned sub-granule
                const bf16x4 sv = *reinterpret_cast<const bf16x4*>(
                    my + p * 64 + g * 8 + (d0 & 7));
                float* orw = ob + (size_t)d0 * HWSZ + p;
#pragma unroll
                for (int r = 0; r < 4; ++r) {
                    float mixed = acc[mt][nt][r] + bb[r];
                    float act = fmaxf(mixed, 0.2f * mixed);         // RReLU (slope>0)
                    float xv = fmaf(LN2, __builtin_log2f((float)sv[r]), Mp[nt]);
                    float v = fmaf(0.1f, xv, act);
                    orw[(size_t)r * HWSZ] = fmaxf(v, 0.f);
                }
            }
        }
    }
}

__global__ __launch_bounds__(256, 3) void fused_kernel(
    const float* __restrict__ x, const __bf16* __restrict__ mixb,
    const float* __restrict__ bias, float* __restrict__ out)
{
    // per-wave 64x64 bf16 s-tile; waves independent -> no __syncthreads
    __shared__ __bf16 sT[4][64 * 64];
    const int tid = threadIdx.x, wid = tid >> 6, lane = tid & 63;
    const int w = blockIdx.x * 4 + wid;           // 8192 waves, 2 tiles each
    const int gp0 = w << 7;                       // 128-pixel base (same image)
    const int b = gp0 >> 16;
    const int hw0 = gp0 & (HWSZ - 1);
    const size_t ibase0 = (size_t)b * (64 * HWSZ) + hw0;
    __bf16* my = &sT[wid][0];
    const int l15 = lane & 15, lhi = lane >> 4;

    float e[64];
    const float* xp0 = x + ibase0 + lane;
#pragma unroll
    for (int c = 0; c < 64; ++c) e[c] = xp0[(size_t)c << 16];     // tile 0 loads

    // ---- tile 0: softmax; then PREFETCH tile 1 into dead e[] before compute ----
    float Mv = softmax_to_lds(e, my, lane);
    const float* xp1 = xp0 + 64;
#pragma unroll
    for (int c = 0; c < 64; ++c) e[c] = xp1[(size_t)c << 16];     // in flight under MFMA
    asm volatile("s_waitcnt lgkmcnt(0)" ::: "memory");            // LDS visibility (wave-local)
    float Mp[4];
#pragma unroll
    for (int nt = 0; nt < 4; ++nt) Mp[nt] = __shfl(Mv, nt * 16 + l15, 64);
    mfma_epilogue(my, mixb, bias, out + ibase0, Mp, l15, lhi);

    // ---- tile 1 ----
    Mv = softmax_to_lds(e, my, lane);             // compiler waits vmcnt as needed
    asm volatile("s_waitcnt lgkmcnt(0)" ::: "memory");
#pragma unroll
    for (int nt = 0; nt < 4; ++nt) Mp[nt] = __shfl(Mv, nt * 16 + l15, 64);
    mfma_epilogue(my, mixb, bias, out + ibase0 + 64, Mp, l15, lhi);
}

extern "C" void kernel_launch(void* const* d_in, const int* in_sizes, int n_in,
                              void* d_out, int out_size, void* d_ws, size_t ws_size,
                              hipStream_t stream) {
    const float* x    = (const float*)d_in[0];
    const float* mix  = (const float*)d_in[1];
    const float* bias = (const float*)d_in[2];
    float* out = (float*)d_out;
    __bf16* mixb = (__bf16*)d_ws;    // 4096 * 2B
    (void)in_sizes; (void)n_in; (void)out_size; (void)ws_size;

    cvt_mix_kernel<<<dim3(16), dim3(256), 0, stream>>>(mix, mixb);
    fused_kernel<<<dim3(2048), dim3(256), 0, stream>>>(x, mixb, bias, out);
}

// Round 6
// 121.292 us; speedup vs baseline: 1.8691x; 1.8691x over previous
//
#include <hip/hip_runtime.h>
#include <math.h>

// (B,C,H,W) = (16,64,256,256)
// out[b,d,hw] = relu( rrelu( sum_c mix[d,c]*softmax_c(x)[b,c,hw] + bias[d] ) + 0.1*x[b,d,hw] )
#define HWSZ 65536

typedef __bf16 bf16x8 __attribute__((ext_vector_type(8)));
typedef __bf16 bf16x4 __attribute__((ext_vector_type(4)));
typedef float f32x4 __attribute__((ext_vector_type(4)));

__global__ __launch_bounds__(256) void cvt_mix_kernel(const float* __restrict__ mix,
                                                      __bf16* __restrict__ mixb) {
    int i = blockIdx.x * 256 + threadIdx.x;   // 4096 elements
    mixb[i] = (__bf16)mix[i];
}

// DMA one 64ch x 64px f32 tile global -> LDS [c][p], zero VGPR cost.
// instr i: lane l -> global (c = i*4 + l/16, pixels (l%16)*4..+3); LDS linear matches.
__device__ __forceinline__ void stage_tile(const float* gsrc, float* ldsdst, int lane) {
    const float* g = gsrc + (size_t)(lane >> 4) * HWSZ + (lane & 15) * 4;
#pragma unroll
    for (int i = 0; i < 16; ++i) {
        __builtin_amdgcn_global_load_lds(
            (const __attribute__((address_space(1))) void*)(g + (size_t)(i * 4) * HWSZ),
            (__attribute__((address_space(3))) void*)(ldsdst + i * 256),
            16, 0, 0);
    }
}

// softmax over e[64]; writes swizzled bf16 s-row `lane`; returns M = m + ln(sum).
__device__ __forceinline__ float softmax_to_lds(float (&e)[64], __bf16* my, int lane) {
    const float LOG2E = 1.44269504088896340736f;
    const float LN2   = 0.69314718055994530942f;
    float m0 = e[0], m1 = e[1], m2 = e[2], m3 = e[3];
#pragma unroll
    for (int c = 4; c < 64; c += 4) {
        m0 = fmaxf(m0, e[c]);     m1 = fmaxf(m1, e[c + 1]);
        m2 = fmaxf(m2, e[c + 2]); m3 = fmaxf(m3, e[c + 3]);
    }
    const float m = fmaxf(fmaxf(m0, m1), fmaxf(m2, m3));
    float s0 = 0.f, s1 = 0.f, s2 = 0.f, s3 = 0.f;
#pragma unroll
    for (int c = 0; c < 64; c += 4) {
        e[c]     = __builtin_exp2f((e[c]     - m) * LOG2E); s0 += e[c];
        e[c + 1] = __builtin_exp2f((e[c + 1] - m) * LOG2E); s1 += e[c + 1];
        e[c + 2] = __builtin_exp2f((e[c + 2] - m) * LOG2E); s2 += e[c + 2];
        e[c + 3] = __builtin_exp2f((e[c + 3] - m) * LOG2E); s3 += e[c + 3];
    }
    const float sum = (s0 + s1) + (s2 + s3);
    const float inv = 1.f / sum;
#pragma unroll
    for (int j = 0; j < 8; ++j) {
        bf16x8 v;
#pragma unroll
        for (int i = 0; i < 8; ++i) v[i] = (__bf16)(e[j * 8 + i] * inv);
        const int gr = j ^ (lane & 7);                    // 16B-granule XOR swizzle
        *reinterpret_cast<bf16x8*>(my + lane * 64 + gr * 8) = v;
    }
    return fmaf(LN2, __builtin_log2f(sum), m);
}

// MFMA matvec + bias/RReLU/0.1x/ReLU epilogue for one tile (ob = out + tile base)
__device__ __forceinline__ void mfma_epilogue(const __bf16* my, const __bf16* mixb,
                                              const float* bias, float* ob,
                                              const float (&Mp)[4], int l15, int lhi) {
    const float LN2 = 0.69314718055994530942f;
#pragma unroll
    for (int mtp = 0; mtp < 2; ++mtp) {
        f32x4 acc[2][4] = {};
#pragma unroll
        for (int kt = 0; kt < 2; ++kt) {
            const __bf16* ab = mixb + (mtp * 32 + l15) * 64 + kt * 32 + lhi * 8;
            const bf16x8 A0 = *reinterpret_cast<const bf16x8*>(ab);
            const bf16x8 A1 = *reinterpret_cast<const bf16x8*>(ab + 16 * 64);
#pragma unroll
            for (int nt = 0; nt < 4; ++nt) {
                const int row = nt * 16 + l15;            // pixel
                const int g = (kt * 4 + lhi) ^ (row & 7);
                const bf16x8 B = *reinterpret_cast<const bf16x8*>(my + row * 64 + g * 8);
                acc[0][nt] = __builtin_amdgcn_mfma_f32_16x16x32_bf16(A0, B, acc[0][nt], 0, 0, 0);
                acc[1][nt] = __builtin_amdgcn_mfma_f32_16x16x32_bf16(A1, B, acc[1][nt], 0, 0, 0);
            }
        }
#pragma unroll
        for (int mt = 0; mt < 2; ++mt) {
            const int d0 = mtp * 32 + mt * 16 + lhi * 4;
            const float bb[4] = {bias[d0], bias[d0 + 1], bias[d0 + 2], bias[d0 + 3]};
#pragma unroll
            for (int nt = 0; nt < 4; ++nt) {
                const int p = nt * 16 + l15;
                const int g = ((d0 >> 3) ^ (p & 7));      // 8B-aligned sub-granule
                const bf16x4 sv = *reinterpret_cast<const bf16x4*>(
                    my + p * 64 + g * 8 + (d0 & 7));
                float* orw = ob + (size_t)d0 * HWSZ + p;
#pragma unroll
                for (int r = 0; r < 4; ++r) {
                    float mixed = acc[mt][nt][r] + bb[r];
                    float act = fmaxf(mixed, 0.2f * mixed);         // RReLU (slope>0)
                    float xv = fmaf(LN2, __builtin_log2f((float)sv[r]), Mp[nt]);
                    float v = fmaf(0.1f, xv, act);
                    // nt store: don't evict x from L2/L3 (out is never re-read)
                    __builtin_nontemporal_store(fmaxf(v, 0.f), &orw[(size_t)r * HWSZ]);
                }
            }
        }
    }
}

__global__ __launch_bounds__(128) void fused_kernel(
    const float* __restrict__ x, const __bf16* __restrict__ mixb,
    const float* __restrict__ bias, float* __restrict__ out)
{
    // per-wave: 16KB x-stage buffer + 8KB s-tile; 2 waves/block -> 48KB/block
    __shared__ float  XB[2][64 * 64];
    __shared__ __bf16 sT[2][64 * 64];
    const int tid = threadIdx.x, wid = tid >> 6, lane = tid & 63;
    const int w = blockIdx.x * 2 + wid;            // 4096 waves, 4 tiles each
    const size_t gp0 = (size_t)w << 8;             // 256-pixel span (within one image)
    const int b = (int)(gp0 >> 16);
    const int hw0 = (int)(gp0 & (HWSZ - 1));
    const size_t ibase = (size_t)b * ((size_t)64 * HWSZ) + hw0;
    const float* xb = x + ibase;
    float* ob = out + ibase;
    float* myXB = &XB[wid][0];
    __bf16* my = &sT[wid][0];
    const int l15 = lane & 15, lhi = lane >> 4;

    stage_tile(xb, myXB, lane);                    // tile 0 DMA in flight

#pragma unroll
    for (int t = 0; t < 4; ++t) {
        asm volatile("s_waitcnt vmcnt(0)" ::: "memory");   // tile t landed in XB
        float e[64];
#pragma unroll
        for (int c = 0; c < 64; ++c) e[c] = myXB[c * 64 + lane];   // 2-way alias = free
        asm volatile("s_waitcnt lgkmcnt(0)" ::: "memory"); // XB consumed -> safe to restage
        if (t < 3) stage_tile(xb + (t + 1) * 64, myXB, lane);      // in flight under compute

        const float Mv = softmax_to_lds(e, my, lane);
        asm volatile("s_waitcnt lgkmcnt(0)" ::: "memory"); // s-tile visible (wave-local)
        float Mp[4];
#pragma unroll
        for (int nt = 0; nt < 4; ++nt) Mp[nt] = __shfl(Mv, nt * 16 + l15, 64);
        mfma_epilogue(my, mixb, bias, ob + t * 64, Mp, l15, lhi);
    }
}

extern "C" void kernel_launch(void* const* d_in, const int* in_sizes, int n_in,
                              void* d_out, int out_size, void* d_ws, size_t ws_size,
                              hipStream_t stream) {
    const float* x    = (const float*)d_in[0];
    const float* mix  = (const float*)d_in[1];
    const float* bias = (const float*)d_in[2];
    float* out = (float*)d_out;
    __bf16* mixb = (__bf16*)d_ws;    // 4096 * 2B
    (void)in_sizes; (void)n_in; (void)out_size; (void)ws_size;

    cvt_mix_kernel<<<dim3(16), dim3(256), 0, stream>>>(mix, mixb);
    fused_kernel<<<dim3(2048), dim3(128), 0, stream>>>(x, mixb, bias, out);
}